// Round 10
// baseline (216.328 us; speedup 1.0000x reference)
//
#include <hip/hip_runtime.h>

// Quadratic positional encoding, fused:
//   out = (E0@Wr + br) * (E@Wg + bg) + (E*E)@Wb + bb,  E = 36-dim trig encoding
// N=1e6 points, OUT=256. Output 1.02 GB f32 -> store-BW bound (~155us at 6.8TB/s).
// R9: convoy-free pipeline. outt double-buffered (2x32KB); e2 matrix dropped
// from LDS -- its A-fragments are in-register squares of e1's fragments
// (bias 1-row squares to 1, header x,y,sinb,cosb square to the quadratic
// header). 3 barriers/tile, every store pass overlaps the next compute phase.
// LDS = 16KB enc + 64KB outt = exactly 80KB -> 2 blocks/CU.

typedef short bf16x8 __attribute__((ext_vector_type(8)));
typedef float f32x16 __attribute__((ext_vector_type(16)));
typedef float f32x4  __attribute__((ext_vector_type(4)));
typedef unsigned int u32x2 __attribute__((ext_vector_type(2)));

__device__ __forceinline__ unsigned short f2bf(float x) {  // setup only
  unsigned int u = __float_as_uint(x);
  return (unsigned short)((u + 0x7FFFu + ((u >> 16) & 1u)) >> 16);  // RNE
}

// pack 2 f32 -> 2 bf16 (RNE): bits[15:0]=bf16(a), bits[31:16]=bf16(b)
__device__ __forceinline__ unsigned int cvtpk(float a, float b) {
  unsigned int r;
  asm("v_cvt_pk_bf16_f32 %0, %1, %2" : "=v"(r) : "v"(a), "v"(b));
  return r;
}

// elementwise square of a bf16x8 fragment, in-register
__device__ __forceinline__ bf16x8 sqfrag(bf16x8 a) {
  union { bf16x8 h; unsigned int u[4]; } in, out;
  in.h = a;
#pragma unroll
  for (int i = 0; i < 4; ++i) {
    float lo = __uint_as_float(in.u[i] << 16);
    float hi = __uint_as_float(in.u[i] & 0xFFFF0000u);
    out.u[i] = cvtpk(lo * lo, hi * hi);
  }
  return out.h;
}

// a in radians; v_sin/v_cos take revolutions, reduce with fract first
__device__ __forceinline__ void fsincos(float a, float* s, float* c) {
  float r = a * 0.15915494309189535f;
  r = r - floorf(r);
  *s = __builtin_amdgcn_sinf(r);
  *c = __builtin_amdgcn_cosf(r);
}

// Barrier that only drains LDS ops: global stores keep flying. All
// inter-wave dependencies in the tile loop are through LDS (enc/outt).
__device__ __forceinline__ void bar_lgkm() {
  asm volatile("s_waitcnt lgkmcnt(0)" ::: "memory");
  __builtin_amdgcn_s_barrier();
  asm volatile("" ::: "memory");
}

// Reordered K layout (k'):
//   k' 0..31  : freq f = k'>>2, comp {sin px, cos px, sin py, cos py} (orig k = k'+4)
//   k' 32..35 : header {x, y, sin base, cos base} (orig k = 0..3)
//   k' 36     : constant 1.0; B row 36 = bias  -> epilogue is one fma
//   k' 37..47 : zero pad
__global__ __launch_bounds__(512, 4) void qpe_kernel(
    const float* __restrict__ X, const float* __restrict__ Y,
    const float* __restrict__ V, const float* __restrict__ V0,
    const float* __restrict__ Wr, const float* __restrict__ Wg,
    const float* __restrict__ Wb, const float* __restrict__ Br,
    const float* __restrict__ Bg, const float* __restrict__ Bb,
    float* __restrict__ Out, int nt)
{
  __shared__ __align__(16) unsigned short enc[2][64][64];  // e0, e1: 16 KB
  __shared__ __align__(16) float outt[2][32][256];         // 64 KB dbuf staging

  const int tid  = threadIdx.x;
  const int lane = tid & 63;
  const int wid  = tid >> 6;   // wave 0..7 -> col block wid*32
  const int hi   = lane >> 5;  // 0/1
  const int ln   = lane & 31;

  // ---- zero entire enc LDS once (pad rows stay zero forever) ----
  {
    bf16x8 z = {0,0,0,0,0,0,0,0};
    bf16x8* pz = (bf16x8*)(&enc[0][0][0]);
    pz[tid] = z; pz[tid + 512] = z;
  }
  __syncthreads();
  // ---- k'=36 constant-1.0 row (swizzled address, set once; e1's squares to 1) ----
  if (tid < 128) {
    int m = tid >> 6, p = tid & 63;
    int swz = (p & 7) << 4;
    *(unsigned int*)((char*)&enc[m][p][0] + ((64 ^ swz) + 8)) = 0x00003F80u;  // {1.0bf, 0}
  }

  // ---- resident B fragments (3 mats x 3 K-steps, 32 cols/wave) ----
  bf16x8 Bf[3][3];
  {
    const float* const Wm[3] = {Wr, Wg, Wb};
    const float* const Bs[3] = {Br, Bg, Bb};
    int col = wid * 32 + ln;
#pragma unroll
    for (int m = 0; m < 3; ++m) {
#pragma unroll
      for (int s = 0; s < 3; ++s) {
        bf16x8 f;
#pragma unroll
        for (int j = 0; j < 8; ++j) {
          int kp = s * 16 + hi * 8 + j;
          float val = 0.0f;
          if (kp < 32)       val = Wm[m][(kp + 4) * 256 + col];  // freq rows
          else if (kp < 36)  val = Wm[m][(kp - 32) * 256 + col]; // x,y,sinb,cosb
          else if (kp == 36) val = Bs[m][col];                   // bias row
          f[j] = (short)f2bf(val);
        }
        Bf[m][s] = f;
      }
    }
  }
  __syncthreads();

  const float TPF = 62.831853071795864f;  // 2*pi*10
  const int   pl = tid >> 3;              // point-local 0..63
  const int   qq = tid & 7;               // freq 0..7
  const float sc = __int_as_float((124 + qq) << 23);  // 2^(qq-3)
  const int   col = wid * 32 + ln;

  // input prefetch registers (consumed at top of tile, refilled mid-tile)
  size_t pt0 = (size_t)blockIdx.x * 64 + pl;
  float xx = X[pt0], yy = Y[pt0], vv = V[pt0], v0v = V0[pt0];

  for (int t = blockIdx.x; t < nt; t += gridDim.x) {
    // ======== E phase: 64 points x 8 threads (1 freq each) ========
    {
      float wn  = TPF / vv;
      float wn0 = TPF / v0v;
      float xw0 = xx * wn0, yw0 = yy * wn0, xw = xx * wn, yw = yy * wn;
      float sx0, cx0, sy0, cy0, sx, cx, sy, cy;
      fsincos(xw0 * sc, &sx0, &cx0);
      fsincos(yw0 * sc, &sy0, &cy0);
      fsincos(xw  * sc, &sx,  &cx);
      fsincos(yw  * sc, &sy,  &cy);
      int swz = (pl & 7) << 4;
      int off = (8 * qq) ^ swz;
      u32x2 w0; w0[0] = cvtpk(sx0, cx0); w0[1] = cvtpk(sy0, cy0);
      u32x2 w1; w1[0] = cvtpk(sx, cx);   w1[1] = cvtpk(sy, cy);
      *(u32x2*)((char*)&enc[0][pl][0] + off) = w0;
      *(u32x2*)((char*)&enc[1][pl][0] + off) = w1;
      if (qq == 0) {
        float s0, c0, s1, c1;
        fsincos(xw0 * 0.0625f, &s0, &c0);
        fsincos(xw  * 0.0625f, &s1, &c1);
        u32x2 h0; h0[0] = cvtpk(xx, yy); h0[1] = cvtpk(s0, c0);
        u32x2 h1; h1[0] = cvtpk(xx, yy); h1[1] = cvtpk(s1, c1);
        int hoff = 64 ^ swz;   // chunk 4 bytes 0..7 = k'32..35
        *(u32x2*)((char*)&enc[0][pl][0] + hoff) = h0;
        *(u32x2*)((char*)&enc[1][pl][0] + hoff) = h1;
      }
    }
    bar_lgkm();  // barA: enc ready (prev store0's outt[0] reads pre-date prev barC)

    // ======== strip0 (rows 0..31): MFMA + 1-fma epilogue -> outt[0] ========
    {
      bf16x8 A0[3], A1[3];
      int swz2 = (ln & 7) << 4;
#pragma unroll
      for (int s = 0; s < 3; ++s) {
        A0[s] = *(const bf16x8*)((const char*)&enc[0][ln][0] + ((s * 32 + hi * 16) ^ swz2));
        A1[s] = *(const bf16x8*)((const char*)&enc[1][ln][0] + ((s * 32 + hi * 16) ^ swz2));
      }
      f32x16 ar, ag, aq;
#pragma unroll
      for (int i = 0; i < 16; ++i) { ar[i] = 0.f; ag[i] = 0.f; aq[i] = 0.f; }
#pragma unroll
      for (int s = 0; s < 3; ++s) {
        ar = __builtin_amdgcn_mfma_f32_32x32x16_bf16(A0[s], Bf[0][s], ar, 0, 0, 0);
        ag = __builtin_amdgcn_mfma_f32_32x32x16_bf16(A1[s], Bf[1][s], ag, 0, 0, 0);
        aq = __builtin_amdgcn_mfma_f32_32x32x16_bf16(sqfrag(A1[s]), Bf[2][s], aq, 0, 0, 0);
      }
#pragma unroll
      for (int i = 0; i < 16; ++i) {
        int rl = (i & 3) + 8 * (i >> 2) + 4 * hi;
        outt[0][rl][col] = ar[i] * ag[i] + aq[i];
      }
    }
    bar_lgkm();  // barB: outt[0] complete

    // store pass strip0 (plain stores -> L2 write-back) overlapped with strip1
    {
      const float* src = &outt[0][0][0];
      size_t base = (size_t)(t * 64) * 256;
#pragma unroll
      for (int it = 0; it < 4; ++it) {
        int idx = it * 2048 + tid * 4;
        f32x4 v = *(const f32x4*)(src + idx);
        *(f32x4*)(Out + base + idx) = v;
      }
    }
    // ======== strip1 (rows 32..63) -> outt[1] ========
    {
      bf16x8 A0[3], A1[3];
      int p = 32 + ln;
      int swz2 = (p & 7) << 4;
#pragma unroll
      for (int s = 0; s < 3; ++s) {
        A0[s] = *(const bf16x8*)((const char*)&enc[0][p][0] + ((s * 32 + hi * 16) ^ swz2));
        A1[s] = *(const bf16x8*)((const char*)&enc[1][p][0] + ((s * 32 + hi * 16) ^ swz2));
      }
      f32x16 ar, ag, aq;
#pragma unroll
      for (int i = 0; i < 16; ++i) { ar[i] = 0.f; ag[i] = 0.f; aq[i] = 0.f; }
#pragma unroll
      for (int s = 0; s < 3; ++s) {
        ar = __builtin_amdgcn_mfma_f32_32x32x16_bf16(A0[s], Bf[0][s], ar, 0, 0, 0);
        ag = __builtin_amdgcn_mfma_f32_32x32x16_bf16(A1[s], Bf[1][s], ag, 0, 0, 0);
        aq = __builtin_amdgcn_mfma_f32_32x32x16_bf16(sqfrag(A1[s]), Bf[2][s], aq, 0, 0, 0);
      }
      // prefetch next tile's inputs while MFMA/stores fly
      {
        int tn = t + (int)gridDim.x;
        size_t ptn = (size_t)(tn < nt ? tn : t) * 64 + pl;
        xx = X[ptn]; yy = Y[ptn]; vv = V[ptn]; v0v = V0[ptn];
      }
#pragma unroll
      for (int i = 0; i < 16; ++i) {
        int rl = (i & 3) + 8 * (i >> 2) + 4 * hi;
        outt[1][rl][col] = ar[i] * ag[i] + aq[i];
      }
    }
    bar_lgkm();  // barC: outt[1] complete; strip reads of enc done (E may rewrite)

    // store pass strip1; next tile's E phase overlaps this drain
    {
      const float* src = &outt[1][0][0];
      size_t base = (size_t)(t * 64 + 32) * 256;
#pragma unroll
      for (int it = 0; it < 4; ++it) {
        int idx = it * 2048 + tid * 4;
        f32x4 v = *(const f32x4*)(src + idx);
        *(f32x4*)(Out + base + idx) = v;
      }
    }
  }
}

extern "C" void kernel_launch(void* const* d_in, const int* in_sizes, int n_in,
                              void* d_out, int out_size, void* d_ws, size_t ws_size,
                              hipStream_t stream) {
  const float* X  = (const float*)d_in[0];
  const float* Y  = (const float*)d_in[1];
  const float* V  = (const float*)d_in[2];
  const float* V0 = (const float*)d_in[3];
  const float* Wr = (const float*)d_in[4];
  const float* Wg = (const float*)d_in[5];
  const float* Wb = (const float*)d_in[6];
  const float* Br = (const float*)d_in[7];
  const float* Bg = (const float*)d_in[8];
  const float* Bb = (const float*)d_in[9];
  float* Out = (float*)d_out;
  int n  = in_sizes[0];
  int nt = n >> 6;  // N=1e6 is divisible by 64
  // 512 blocks x 512 threads = 2 resident blocks/CU (80KB LDS exactly, 128 VGPR),
  // 16 waves/CU = 4 waves/SIMD.
  qpe_kernel<<<dim3(512), dim3(512), 0, stream>>>(X, Y, V, V0, Wr, Wg, Wb,
                                                  Br, Bg, Bb, Out, nt);
}

// Round 11
// 201.165 us; speedup vs baseline: 1.0754x; 1.0754x over previous
//
#include <hip/hip_runtime.h>

// Quadratic positional encoding, fused:
//   out = (E0@Wr + br) * (E@Wg + bg) + (E*E)@Wb + bb,  E = 36-dim trig encoding
// N=1e6 points, OUT=256. Output 1.02 GB f32 -> store floor ~152us at 6.8TB/s.
// R10: parity-staggered store/compute. R9's timing = store-drain + compute,
// fully serial: all waves issue stores first in each region, stall on the
// backed-up write queue (in-order issue), VALUs idle. Now odd/even waves swap
// {store,compute} order per region so half the waves always have compute in
// flight while the queue drains. Store1 hoisted to next tile's E region.

typedef short bf16x8 __attribute__((ext_vector_type(8)));
typedef float f32x16 __attribute__((ext_vector_type(16)));
typedef float f32x4  __attribute__((ext_vector_type(4)));
typedef unsigned int u32x2 __attribute__((ext_vector_type(2)));

__device__ __forceinline__ unsigned short f2bf(float x) {  // setup only
  unsigned int u = __float_as_uint(x);
  return (unsigned short)((u + 0x7FFFu + ((u >> 16) & 1u)) >> 16);  // RNE
}

// pack 2 f32 -> 2 bf16 (RNE): bits[15:0]=bf16(a), bits[31:16]=bf16(b)
__device__ __forceinline__ unsigned int cvtpk(float a, float b) {
  unsigned int r;
  asm("v_cvt_pk_bf16_f32 %0, %1, %2" : "=v"(r) : "v"(a), "v"(b));
  return r;
}

// elementwise square of a bf16x8 fragment, in-register
__device__ __forceinline__ bf16x8 sqfrag(bf16x8 a) {
  union { bf16x8 h; unsigned int u[4]; } in, out;
  in.h = a;
#pragma unroll
  for (int i = 0; i < 4; ++i) {
    float lo = __uint_as_float(in.u[i] << 16);
    float hi = __uint_as_float(in.u[i] & 0xFFFF0000u);
    out.u[i] = cvtpk(lo * lo, hi * hi);
  }
  return out.h;
}

// a in radians; v_sin/v_cos take revolutions, reduce with fract first
__device__ __forceinline__ void fsincos(float a, float* s, float* c) {
  float r = a * 0.15915494309189535f;
  r = r - floorf(r);
  *s = __builtin_amdgcn_sinf(r);
  *c = __builtin_amdgcn_cosf(r);
}

// Barrier that only drains LDS ops: global stores keep flying. All
// inter-wave dependencies in the tile loop are through LDS (enc/outt).
__device__ __forceinline__ void bar_lgkm() {
  asm volatile("s_waitcnt lgkmcnt(0)" ::: "memory");
  __builtin_amdgcn_s_barrier();
  asm volatile("" ::: "memory");
}

// Reordered K layout (k'):
//   k' 0..31  : freq f = k'>>2, comp {sin px, cos px, sin py, cos py} (orig k = k'+4)
//   k' 32..35 : header {x, y, sin base, cos base} (orig k = 0..3)
//   k' 36     : constant 1.0; B row 36 = bias  -> epilogue is one fma
//   k' 37..47 : zero pad
__global__ __launch_bounds__(512, 4) void qpe_kernel(
    const float* __restrict__ X, const float* __restrict__ Y,
    const float* __restrict__ V, const float* __restrict__ V0,
    const float* __restrict__ Wr, const float* __restrict__ Wg,
    const float* __restrict__ Wb, const float* __restrict__ Br,
    const float* __restrict__ Bg, const float* __restrict__ Bb,
    float* __restrict__ Out, int nt)
{
  __shared__ __align__(16) unsigned short enc[2][64][64];  // e0, e1: 16 KB
  __shared__ __align__(16) float outt[2][32][256];         // 64 KB dbuf staging

  const int tid  = threadIdx.x;
  const int lane = tid & 63;
  const int wid  = tid >> 6;   // wave 0..7 -> col block wid*32
  const int hi   = lane >> 5;  // 0/1
  const int ln   = lane & 31;
  const int wodd = wid & 1;

  // ---- zero entire enc LDS once (pad rows stay zero forever) ----
  {
    bf16x8 z = {0,0,0,0,0,0,0,0};
    bf16x8* pz = (bf16x8*)(&enc[0][0][0]);
    pz[tid] = z; pz[tid + 512] = z;
  }
  __syncthreads();
  // ---- k'=36 constant-1.0 row (swizzled address, set once; e1's squares to 1) ----
  if (tid < 128) {
    int m = tid >> 6, p = tid & 63;
    int swz = (p & 7) << 4;
    *(unsigned int*)((char*)&enc[m][p][0] + ((64 ^ swz) + 8)) = 0x00003F80u;  // {1.0bf, 0}
  }

  // ---- resident B fragments (3 mats x 3 K-steps, 32 cols/wave) ----
  bf16x8 Bf[3][3];
  {
    const float* const Wm[3] = {Wr, Wg, Wb};
    const float* const Bs[3] = {Br, Bg, Bb};
    int col = wid * 32 + ln;
#pragma unroll
    for (int m = 0; m < 3; ++m) {
#pragma unroll
      for (int s = 0; s < 3; ++s) {
        bf16x8 f;
#pragma unroll
        for (int j = 0; j < 8; ++j) {
          int kp = s * 16 + hi * 8 + j;
          float val = 0.0f;
          if (kp < 32)       val = Wm[m][(kp + 4) * 256 + col];  // freq rows
          else if (kp < 36)  val = Wm[m][(kp - 32) * 256 + col]; // x,y,sinb,cosb
          else if (kp == 36) val = Bs[m][col];                   // bias row
          f[j] = (short)f2bf(val);
        }
        Bf[m][s] = f;
      }
    }
  }
  __syncthreads();

  const float TPF = 62.831853071795864f;  // 2*pi*10
  const int   pl = tid >> 3;              // point-local 0..63
  const int   qq = tid & 7;               // freq 0..7
  const float sc = __int_as_float((124 + qq) << 23);  // 2^(qq-3)
  const int   col = wid * 32 + ln;

  // input prefetch registers (consumed at top of tile, refilled mid-tile)
  size_t pt0 = (size_t)blockIdx.x * 64 + pl;
  float xx = X[pt0], yy = Y[pt0], vv = V[pt0], v0v = V0[pt0];

  // ---- store pass helpers (1KB rows, 64 lanes x 16B per instruction) ----
  auto STORE = [&](int buf, size_t rowbase) {
    const float* src = &outt[buf][0][0];
#pragma unroll
    for (int it = 0; it < 4; ++it) {
      int idx = it * 2048 + tid * 4;
      f32x4 v = *(const f32x4*)(src + idx);
      *(f32x4*)(Out + rowbase * 256 + idx) = v;
    }
  };

  auto EPHASE = [&]() {
    float wn  = TPF / vv;
    float wn0 = TPF / v0v;
    float xw0 = xx * wn0, yw0 = yy * wn0, xw = xx * wn, yw = yy * wn;
    float sx0, cx0, sy0, cy0, sx, cx, sy, cy;
    fsincos(xw0 * sc, &sx0, &cx0);
    fsincos(yw0 * sc, &sy0, &cy0);
    fsincos(xw  * sc, &sx,  &cx);
    fsincos(yw  * sc, &sy,  &cy);
    int swz = (pl & 7) << 4;
    int off = (8 * qq) ^ swz;
    u32x2 w0; w0[0] = cvtpk(sx0, cx0); w0[1] = cvtpk(sy0, cy0);
    u32x2 w1; w1[0] = cvtpk(sx, cx);   w1[1] = cvtpk(sy, cy);
    *(u32x2*)((char*)&enc[0][pl][0] + off) = w0;
    *(u32x2*)((char*)&enc[1][pl][0] + off) = w1;
    if (qq == 0) {
      float s0, c0, s1, c1;
      fsincos(xw0 * 0.0625f, &s0, &c0);
      fsincos(xw  * 0.0625f, &s1, &c1);
      u32x2 h0; h0[0] = cvtpk(xx, yy); h0[1] = cvtpk(s0, c0);
      u32x2 h1; h1[0] = cvtpk(xx, yy); h1[1] = cvtpk(s1, c1);
      int hoff = 64 ^ swz;   // chunk 4 bytes 0..7 = k'32..35
      *(u32x2*)((char*)&enc[0][pl][0] + hoff) = h0;
      *(u32x2*)((char*)&enc[1][pl][0] + hoff) = h1;
    }
  };

  auto STRIP = [&](int p, int buf) {
    bf16x8 A0[3], A1[3];
    int swz2 = (p & 7) << 4;
#pragma unroll
    for (int s = 0; s < 3; ++s) {
      A0[s] = *(const bf16x8*)((const char*)&enc[0][p][0] + ((s * 32 + hi * 16) ^ swz2));
      A1[s] = *(const bf16x8*)((const char*)&enc[1][p][0] + ((s * 32 + hi * 16) ^ swz2));
    }
    f32x16 ar, ag, aq;
#pragma unroll
    for (int i = 0; i < 16; ++i) { ar[i] = 0.f; ag[i] = 0.f; aq[i] = 0.f; }
#pragma unroll
    for (int s = 0; s < 3; ++s) {
      ar = __builtin_amdgcn_mfma_f32_32x32x16_bf16(A0[s], Bf[0][s], ar, 0, 0, 0);
      ag = __builtin_amdgcn_mfma_f32_32x32x16_bf16(A1[s], Bf[1][s], ag, 0, 0, 0);
      aq = __builtin_amdgcn_mfma_f32_32x32x16_bf16(sqfrag(A1[s]), Bf[2][s], aq, 0, 0, 0);
    }
#pragma unroll
    for (int i = 0; i < 16; ++i) {
      int rl = (i & 3) + 8 * (i >> 2) + 4 * hi;
      outt[buf][rl][col] = ar[i] * ag[i] + aq[i];
    }
  };

  int tprev = -1;  // tile whose strip1 result sits in outt[1]
  for (int t = blockIdx.x; t < nt; t += gridDim.x) {
    // ---- region1: E(t) || store1(tprev), parity-staggered ----
    if (wodd) {
      EPHASE();
      if (tprev >= 0) STORE(1, (size_t)tprev * 64 + 32);
    } else {
      if (tprev >= 0) STORE(1, (size_t)tprev * 64 + 32);
      EPHASE();
    }
    bar_lgkm();  // barA: enc ready; store1's outt[1] reads drained

    // ---- region2: strip0 -> outt[0] ----
    STRIP(ln, 0);
    bar_lgkm();  // barB: outt[0] complete

    // ---- region3: store0 || strip1 -> outt[1], parity-staggered (roles swapped) ----
    if (wodd) {
      STORE(0, (size_t)t * 64);
      STRIP(32 + ln, 1);
    } else {
      STRIP(32 + ln, 1);
      STORE(0, (size_t)t * 64);
    }
    // prefetch next tile's inputs (tiny; overlaps store drain)
    {
      int tn = t + (int)gridDim.x;
      size_t ptn = (size_t)(tn < nt ? tn : t) * 64 + pl;
      xx = X[ptn]; yy = Y[ptn]; vv = V[ptn]; v0v = V0[ptn];
    }
    bar_lgkm();  // barC: outt[1] complete; enc reads done (next E may rewrite)
    tprev = t;
  }
  // final strip1 store
  STORE(1, (size_t)tprev * 64 + 32);
}

extern "C" void kernel_launch(void* const* d_in, const int* in_sizes, int n_in,
                              void* d_out, int out_size, void* d_ws, size_t ws_size,
                              hipStream_t stream) {
  const float* X  = (const float*)d_in[0];
  const float* Y  = (const float*)d_in[1];
  const float* V  = (const float*)d_in[2];
  const float* V0 = (const float*)d_in[3];
  const float* Wr = (const float*)d_in[4];
  const float* Wg = (const float*)d_in[5];
  const float* Wb = (const float*)d_in[6];
  const float* Br = (const float*)d_in[7];
  const float* Bg = (const float*)d_in[8];
  const float* Bb = (const float*)d_in[9];
  float* Out = (float*)d_out;
  int n  = in_sizes[0];
  int nt = n >> 6;  // N=1e6 is divisible by 64
  // 512 blocks x 512 threads = 2 resident blocks/CU (80KB LDS exactly, 128 VGPR),
  // 16 waves/CU = 4 waves/SIMD.
  qpe_kernel<<<dim3(512), dim3(512), 0, stream>>>(X, Y, V, V0, Wr, Wg, Wb,
                                                  Br, Bg, Bb, Out, nt);
}